// Round 2
// baseline (739.743 us; speedup 1.0000x reference)
//
#include <hip/hip_runtime.h>
#include <hip/hip_bf16.h>
#include <cstddef>

#define B_ 16
#define H_ 256
#define W_ 256
#define HW_ (H_ * W_)
#define P_ 258  // padded H/W for planar activation buffers

// Activation layout is channel-group-PLANAR: [B][C/8][258][258][8] fp16.
// Plane q holds channels q*8..q*8+7. Conv stage-DMA global addresses are
// contiguous in the staging loop index (1KB coalesced per wave instruction)
// while the LDS layout s_in[q][row][col][8] matches MFMA fragment needs.

typedef _Float16 half8 __attribute__((ext_vector_type(8)));
typedef float floatx4 __attribute__((ext_vector_type(4)));

// async global->LDS 16B DMA (LDS dest must be wave-uniform base + lane*16;
// all call sites keep lds offset strictly linear in the per-lane loop index)
__device__ __forceinline__ void gload_lds16(void* lds, const void* g) {
  __builtin_amdgcn_global_load_lds(
      (const __attribute__((address_space(1))) unsigned int*)g,
      (__attribute__((address_space(3))) unsigned int*)lds, 16, 0, 0);
}

// ---------------------------------------------------------------------------
// Zero the 1-pixel border of all three planar activation buffers in ONE
// launch: feat [16][4][258][258][8], actA/actB [16][8][258][258][8] fp16.
// (ws is re-poisoned 0xAA before every launch, so this runs every call.)
// ---------------------------------------------------------------------------
__global__ __launch_bounds__(256) void zero_border3(_Float16* __restrict__ f,
                                                    _Float16* __restrict__ a,
                                                    _Float16* __restrict__ bb) {
  int idx = blockIdx.x * 256 + threadIdx.x;
  int total = 16 * 20 * 1028;
  if (idx >= total) return;
  int p = idx % 1028;
  int rest = idx / 1028;
  int cg = rest % 20;
  int b = rest / 20;
  _Float16* buf;
  int ncg, c;
  if (cg < 4) { buf = f; ncg = 4; c = cg; }
  else if (cg < 12) { buf = a; ncg = 8; c = cg - 4; }
  else { buf = bb; ncg = 8; c = cg - 12; }
  int row, col;
  if (p < 258) { row = 0; col = p; }
  else if (p < 516) { row = 257; col = p - 258; }
  else if (p < 772) { row = p - 515; col = 0; }
  else { row = p - 771; col = 257; }
  *(floatx4*)&buf[(((size_t)(b * ncg + c) * P_ + row) * P_ + col) * 8] =
      (floatx4)0.f;
}

// ---------------------------------------------------------------------------
// Feature extraction: x [B,3,H,W] fp32 -> F planar [B][4][258][258][8] fp16
// ---------------------------------------------------------------------------
__global__ __launch_bounds__(256) void feat_kernel(const float* __restrict__ x,
                                                   _Float16* __restrict__ F) {
  __shared__ float sg[36][37];
  __shared__ float sgr[36][37];

  const int b = blockIdx.z;
  const int y0 = blockIdx.y * 32;
  const int x0 = blockIdx.x * 32;
  const float* xb = x + (size_t)b * 3 * HW_;

  for (int i = threadIdx.x; i < 36 * 36; i += 256) {
    int iy = i / 36, ix = i % 36;
    int gy = y0 + iy - 2, gx = x0 + ix - 2;
    float gray = 0.f, green = 0.f;
    if (gy >= 0 && gy < H_ && gx >= 0 && gx < W_) {
      int idx = gy * W_ + gx;
      float r = fminf(fmaxf(xb[idx] * 0.229f + 0.485f, 0.f), 1.f);
      float g = fminf(fmaxf(xb[idx + HW_] * 0.224f + 0.456f, 0.f), 1.f);
      float bl = fminf(fmaxf(xb[idx + 2 * HW_] * 0.225f + 0.406f, 0.f), 1.f);
      gray = 0.299f * r + 0.587f * g + 0.114f * bl;
      green = g;
    }
    sg[iy][ix] = gray;
    sgr[iy][ix] = green;
  }
  __syncthreads();

  for (int p = threadIdx.x; p < 32 * 32; p += 256) {
    const int py = p >> 5, px = p & 31;
    const int ly = py + 2, lx = px + 2;
#define G(dy, dx) sg[ly + (dy)][lx + (dx)]
    float f[32];
    const float c = G(0, 0);

    {
      const float ga[5] = {1.f, 4.f, 6.f, 4.f, 1.f};
      float s = 0.f;
#pragma unroll
      for (int i = 0; i < 5; i++) {
        float rs = 0.f;
#pragma unroll
        for (int j = 0; j < 5; j++) rs += ga[j] * G(i - 2, j - 2);
        s += ga[i] * rs;
      }
      f[0] = c - s * (1.0f / 256.0f);
    }

    const int dy8[8] = {-1, -1, 0, 1, 1, 1, 0, -1};
    const int dx8[8] = {0, 1, 1, 1, 0, -1, -1, -1};

#pragma unroll
    for (int k = 0; k < 8; k++) f[1 + k] = G(dy8[k], dx8[k]) - c;
#pragma unroll
    for (int k = 0; k < 4; k++)
      f[9 + k] = 0.5f * (G(dy8[k], dx8[k]) + G(-dy8[k], -dx8[k])) - c;
#pragma unroll
    for (int k = 0; k < 8; k++)
      f[13 + k] = (-G(-dy8[k], -dx8[k]) + 3.f * c - 3.f * G(dy8[k], dx8[k]) +
                   G(2 * dy8[k], 2 * dx8[k])) * (1.f / 3.f);

    {
      const float sq3[3][3] = {{-1, 2, -1}, {2, -4, 2}, {-1, 2, -1}};
      float s = 0.f;
#pragma unroll
      for (int i = 0; i < 3; i++)
#pragma unroll
        for (int j = 0; j < 3; j++) s += sq3[i][j] * G(i - 1, j - 1);
      f[21] = s * 0.25f;
    }
    {
      const float sq5[5][5] = {{-1, 2, -2, 2, -1},
                               {2, -6, 8, -6, 2},
                               {-2, 8, -12, 8, -2},
                               {2, -6, 8, -6, 2},
                               {-1, 2, -2, 2, -1}};
      float s = 0.f;
#pragma unroll
      for (int i = 0; i < 5; i++)
#pragma unroll
        for (int j = 0; j < 5; j++) s += sq5[i][j] * G(i - 2, j - 2);
      f[22] = s * (1.0f / 12.0f);
    }
    {
      const float e3[3][3] = {{-1, 2, -1}, {2, -4, 2}, {0, 0, 0}};
      float s0 = 0.f, s1 = 0.f, s2 = 0.f, s3 = 0.f;
#pragma unroll
      for (int i = 0; i < 3; i++)
#pragma unroll
        for (int j = 0; j < 3; j++) {
          float v = G(i - 1, j - 1);
          s0 += e3[i][j] * v;
          s1 += e3[j][2 - i] * v;
          s2 += e3[2 - i][2 - j] * v;
          s3 += e3[2 - j][i] * v;
        }
      f[23] = s0 * 0.25f;
      f[24] = s1 * 0.25f;
      f[25] = s2 * 0.25f;
      f[26] = s3 * 0.25f;
    }
    {
      const float e5[5][5] = {{-1, 2, -2, 2, -1},
                              {2, -6, 8, -6, 2},
                              {-2, 8, -12, 8, -2},
                              {0, 0, 0, 0, 0},
                              {0, 0, 0, 0, 0}};
      float s0 = 0.f, s1 = 0.f, s2 = 0.f, s3 = 0.f;
#pragma unroll
      for (int i = 0; i < 5; i++)
#pragma unroll
        for (int j = 0; j < 5; j++) {
          float v = G(i - 2, j - 2);
          s0 += e5[i][j] * v;
          s1 += e5[j][4 - i] * v;
          s2 += e5[4 - i][4 - j] * v;
          s3 += e5[4 - j][i] * v;
        }
      f[27] = s0 * 0.25f;
      f[28] = s1 * 0.25f;
      f[29] = s2 * 0.25f;
      f[30] = s3 * 0.25f;
    }
    {
      float gc = sgr[ly][lx];
      f[31] = gc - 0.25f * (sgr[ly - 1][lx] + sgr[ly][lx - 1] +
                            sgr[ly][lx + 1] + sgr[ly + 1][lx]);
    }
#undef G

    _Float16 h[32];
#pragma unroll
    for (int cc = 0; cc < 32; cc++) h[cc] = (_Float16)f[cc];
    const floatx4* src = (const floatx4*)h;
#pragma unroll
    for (int cg = 0; cg < 4; cg++)
      *(floatx4*)&F[(((size_t)(b * 4 + cg) * P_ + (y0 + py + 1)) * P_ +
                     (x0 + px + 1)) * 8] = src[cg];
  }
}

// ---------------------------------------------------------------------------
// Weight prep (all 4 layers in ONE launch, blockIdx.y = layer):
// OIHW fp32 -> [cin/8][9][64][8] fp16 + folded BN scale/shift.
// Layout matches conv LDS layout exactly -> pure contiguous DMA staging.
// ---------------------------------------------------------------------------
__global__ void wprep4_kernel(
    const float* __restrict__ w1, const float* __restrict__ b1,
    const float* __restrict__ g1, const float* __restrict__ be1,
    const float* __restrict__ m1, const float* __restrict__ v1,
    const float* __restrict__ w2, const float* __restrict__ b2,
    const float* __restrict__ g2, const float* __restrict__ be2,
    const float* __restrict__ m2, const float* __restrict__ v2,
    const float* __restrict__ w3, const float* __restrict__ b3,
    const float* __restrict__ g3, const float* __restrict__ be3,
    const float* __restrict__ m3, const float* __restrict__ v3,
    const float* __restrict__ w4, const float* __restrict__ b4,
    const float* __restrict__ g4, const float* __restrict__ be4,
    const float* __restrict__ m4, const float* __restrict__ v4,
    _Float16* __restrict__ wp1, _Float16* __restrict__ wp2,
    _Float16* __restrict__ wp3, _Float16* __restrict__ wp4,
    float* __restrict__ scsh) {
  const int layer = blockIdx.y;
  const float *w, *bias, *g, *be, *m, *v;
  _Float16* wp;
  int cin;
  switch (layer) {
    case 0: w = w1; bias = b1; g = g1; be = be1; m = m1; v = v1; wp = wp1; cin = 32; break;
    case 1: w = w2; bias = b2; g = g2; be = be2; m = m2; v = v2; wp = wp2; cin = 64; break;
    case 2: w = w3; bias = b3; g = g3; be = be3; m = m3; v = v3; wp = wp3; cin = 64; break;
    default: w = w4; bias = b4; g = g4; be = be4; m = m4; v = v4; wp = wp4; cin = 64; break;
  }
  int i = blockIdx.x * 256 + threadIdx.x;
  int total = cin * 9 * 64;
  if (i < total) {
    int j = i & 7;
    int co = (i >> 3) & 63;
    int rest = i >> 9;
    int t = rest % 9;
    int qc = rest / 9;
    int ci = qc * 8 + j;
    wp[i] = (_Float16)w[((size_t)co * cin + ci) * 9 + t];
  }
  if (i < 64) {
    float s = g[i] * rsqrtf(v[i] + 1e-5f);
    scsh[layer * 128 + i] = s;
    scsh[layer * 128 + 64 + i] = be[i] + (bias[i] - m[i]) * s;
  }
}

// ---------------------------------------------------------------------------
// Implicit-GEMM conv3x3 + BN + ReLU via mfma_f32_16x16x32_f16.
// in: PLANAR fp16 [B][CIN/8][258][258][8].  wp: [CIN/8][9][64][8] fp16.
// Block: 64(x) x 8(y) pixels, all 64 couts. 4 waves; wave w owns rows 2w,2w+1.
// Wave tile: M=128 x N=64 = 8x4 MFMA tiles.
//
// STAGE-ONCE structure: the ENTIRE input window (CIN/8 planes x 10 x 66) and
// the ENTIRE weight table are DMA'd in one prologue, then ONE barrier, then
// all CIN/32 k-chunks x 9 taps of MFMA run with zero mid-kernel vmcnt(0)
// drains (the former per-kc stage->drain->barrier serialization was the
// dominant stall; compute has 4x ILP slack: 32 MFMA ~620cy vs 12 ds_read
// ~144cy per tap). CIN=64: 158,208B LDS -> 1 block/CU. CIN=32: 79,104B ->
// 2 blocks/CU (structure was already stage-once there).
// FINAL=false: out planar fp16 (LDS bounce, XOR-swizzled). FINAL=true: NCHW f32.
// ---------------------------------------------------------------------------
template <int CIN, bool FINAL>
__global__ __launch_bounds__(256, CIN == 32 ? 2 : 1) void conv_mfma(
    const _Float16* __restrict__ in, const _Float16* __restrict__ wp,
    const float* __restrict__ sc, const float* __restrict__ sh,
    void* __restrict__ outv) {
  constexpr int NP = CIN / 8;                      // cin planes
  constexpr int IN_BYTES = NP * 10 * 66 * 8 * 2;   // 42,240 / 84,480
  constexpr int W_BYTES = NP * 9 * 64 * 8 * 2;     // 36,864 / 73,728
  constexpr int IN_UNITS = NP * 10 * 66;           // 16B units
  constexpr int W_UNITS = W_BYTES / 16;

  __shared__ char smem[IN_BYTES + W_BYTES];
  _Float16(*s_in)[10][66][8] = (_Float16(*)[10][66][8])smem;
  _Float16(*s_w)[9][64][8] = (_Float16(*)[9][64][8])(smem + IN_BYTES);

  const int tid = threadIdx.x;
  const int b = blockIdx.z;
  const int y0 = blockIdx.y * 8;
  const int x0 = blockIdx.x * 64;
  const int wid = tid >> 6;
  const int lane = tid & 63;
  const int quad = lane >> 4;
  const int ln = lane & 15;

  floatx4 acc[8][4];
#pragma unroll
  for (int mt = 0; mt < 8; mt++)
#pragma unroll
    for (int nt = 0; nt < 4; nt++) acc[mt][nt] = (floatx4)0.f;

  // ---- prologue: stage ALL input planes + ALL weights, one barrier ----
  for (int i = tid; i < IN_UNITS; i += 256) {
    int q = i / 660, rem = i % 660;
    int row = rem / 66, col = rem % 66;
    gload_lds16(smem + i * 16,
                &in[(((size_t)(b * NP + q) * P_ + (y0 + row)) * P_ +
                     (x0 + col)) * 8]);
  }
  for (int i = tid; i < W_UNITS; i += 256) {
    gload_lds16(smem + IN_BYTES + i * 16, wp + (size_t)i * 8);
  }
  __syncthreads();

  // ---- straight-line compute: no further syncs/drains until epilogue ----
  for (int kc = 0; kc < NP / 4; kc++) {
#pragma unroll
    for (int t = 0; t < 9; t++) {
      const int ty = t / 3, tx = t % 3;
      half8 a[8], bb[4];
#pragma unroll
      for (int nt = 0; nt < 4; nt++)
        bb[nt] = *(const half8*)&s_w[kc * 4 + quad][t][nt * 16 + ln][0];
#pragma unroll
      for (int mt = 0; mt < 8; mt++)
        a[mt] = *(const half8*)&s_in[kc * 4 + quad]
                                    [2 * wid + ty + (mt >> 2)]
                                    [(mt & 3) * 16 + ln + tx][0];
#pragma unroll
      for (int mt = 0; mt < 8; mt++)
#pragma unroll
        for (int nt = 0; nt < 4; nt++)
          acc[mt][nt] = __builtin_amdgcn_mfma_f32_16x16x32_f16(
              a[mt], bb[nt], acc[mt][nt], 0, 0, 0);
    }
  }

  if (FINAL) {
    // NCHW fp32 direct: in-lane 4 accs = 4 consecutive x -> dwordx4 stores
    float* out = (float*)outv;
#pragma unroll
    for (int nt = 0; nt < 4; nt++) {
      int co = nt * 16 + ln;
      float s = sc[co], t0 = sh[co];
#pragma unroll
      for (int mt = 0; mt < 8; mt++) {
        int y = y0 + 2 * wid + (mt >> 2);
        int xb = x0 + (mt & 3) * 16 + quad * 4;
        floatx4 vv;
#pragma unroll
        for (int r = 0; r < 4; r++) vv[r] = fmaxf(acc[mt][nt][r] * s + t0, 0.f);
        *(floatx4*)&out[(((size_t)b * 64 + co) * H_ + y) * W_ + xb] = vv;
      }
    }
  } else {
    // planar fp16 out via per-wave 16KB LDS bounce (smem reused).
    // s_out logical layout: [pix 0..127][co 0..63], channel-group slot
    // XOR-swizzled by (pix&7) so the plane-major 16B re-read (lane = pix,
    // stride 128B) spreads across all 32 banks instead of hitting 4.
    __syncthreads();  // all MFMA LDS reads done before overwrite
    _Float16* s_out = (_Float16*)smem + wid * 8192;
#pragma unroll
    for (int nt = 0; nt < 4; nt++) {
      int co = nt * 16 + ln;
      float s = sc[co], t0 = sh[co];
      int cog = co >> 3, clo = co & 7;
#pragma unroll
      for (int mt = 0; mt < 8; mt++) {
        int pix0 = (mt >> 2) * 64 + (mt & 3) * 16 + quad * 4;
#pragma unroll
        for (int r = 0; r < 4; r++) {
          int pix = pix0 + r;
          s_out[pix * 64 + (((cog ^ (pix & 7)) << 3) | clo)] =
              (_Float16)fmaxf(acc[mt][nt][r] * s + t0, 0.f);
        }
      }
    }
    __builtin_amdgcn_s_waitcnt(0);  // lgkmcnt(0): own-wave LDS writes visible
    _Float16* out = (_Float16*)outv;
#pragma unroll
    for (int k = 0; k < 16; k++) {
      int rw = k >> 3, cog = k & 7;
      int pix = rw * 64 + lane;
      int gy = y0 + 2 * wid + rw + 1, gx = x0 + lane + 1;
      *(floatx4*)&out[(((size_t)(b * 8 + cog) * P_ + gy) * P_ + gx) * 8] =
          *(const floatx4*)&s_out[pix * 64 + ((cog ^ (lane & 7)) << 3)];
    }
  }
}

// ---------------------------------------------------------------------------
// Launch
// ---------------------------------------------------------------------------
extern "C" void kernel_launch(void* const* d_in, const int* in_sizes, int n_in,
                              void* d_out, int out_size, void* d_ws,
                              size_t ws_size, hipStream_t stream) {
  const float* x = (const float*)d_in[0];
#define LAYER_PTRS(i)                                                       \
  const float* w##i = (const float*)d_in[1 + ((i)-1) * 6 + 0];              \
  const float* b##i = (const float*)d_in[1 + ((i)-1) * 6 + 1];              \
  const float* g##i = (const float*)d_in[1 + ((i)-1) * 6 + 2];              \
  const float* be##i = (const float*)d_in[1 + ((i)-1) * 6 + 3];             \
  const float* m##i = (const float*)d_in[1 + ((i)-1) * 6 + 4];              \
  const float* v##i = (const float*)d_in[1 + ((i)-1) * 6 + 5];
  LAYER_PTRS(1)
  LAYER_PTRS(2)
  LAYER_PTRS(3)
  LAYER_PTRS(4)
#undef LAYER_PTRS

  char* ws = (char*)d_ws;
  const size_t featB = (size_t)16 * 4 * P_ * P_ * 8 * 2;   // 68,161,536
  const size_t actB64 = (size_t)16 * 8 * P_ * P_ * 8 * 2;  // 136,323,072
  _Float16* feat = (_Float16*)ws;
  _Float16* actA = (_Float16*)(ws + featB);
  _Float16* actB = (_Float16*)(ws + featB + actB64);
  char* wbase = ws + featB + 2 * actB64;
  _Float16* wp1 = (_Float16*)(wbase);
  _Float16* wp2 = (_Float16*)(wbase + 36864);
  _Float16* wp3 = (_Float16*)(wbase + 36864 + 73728);
  _Float16* wp4 = (_Float16*)(wbase + 36864 + 2 * 73728);
  float* scsh = (float*)(wbase + 36864 + 3 * 73728);
  float *sc1 = scsh, *sh1 = scsh + 64;
  float *sc2 = scsh + 128, *sh2 = scsh + 192;
  float *sc3 = scsh + 256, *sh3 = scsh + 320;
  float *sc4 = scsh + 384, *sh4 = scsh + 448;

  dim3 wgrid(144, 4);
  wprep4_kernel<<<wgrid, 256, 0, stream>>>(
      w1, b1, g1, be1, m1, v1, w2, b2, g2, be2, m2, v2,
      w3, b3, g3, be3, m3, v3, w4, b4, g4, be4, m4, v4,
      wp1, wp2, wp3, wp4, scsh);

  zero_border3<<<1285, 256, 0, stream>>>(feat, actA, actB);

  dim3 fgrid(W_ / 32, H_ / 32, B_);
  feat_kernel<<<fgrid, 256, 0, stream>>>(x, feat);

  dim3 cgrid(W_ / 64, H_ / 8, B_);
  conv_mfma<32, false><<<cgrid, 256, 0, stream>>>(feat, wp1, sc1, sh1, actA);
  conv_mfma<64, false><<<cgrid, 256, 0, stream>>>(actA, wp2, sc2, sh2, actB);
  conv_mfma<64, false><<<cgrid, 256, 0, stream>>>(actB, wp3, sc3, sh3, actA);
  conv_mfma<64, true><<<cgrid, 256, 0, stream>>>(actA, wp4, sc4, sh4, d_out);
}

// Round 3
// 696.942 us; speedup vs baseline: 1.0614x; 1.0614x over previous
//
#include <hip/hip_runtime.h>
#include <hip/hip_bf16.h>
#include <cstddef>

#define B_ 16
#define H_ 256
#define W_ 256
#define HW_ (H_ * W_)
#define P_ 258  // padded H/W for planar activation buffers

// Activation layout is channel-group-PLANAR: [B][C/8][258][258][8] fp16.
// Plane q holds channels q*8..q*8+7. Conv stage-DMA global addresses are
// contiguous in the staging loop index (1KB coalesced per wave instruction)
// while the LDS layout s_in[q][row][col][8] matches MFMA fragment needs.

typedef _Float16 half8 __attribute__((ext_vector_type(8)));
typedef float floatx4 __attribute__((ext_vector_type(4)));

// async global->LDS 16B DMA (LDS dest must be wave-uniform base + lane*16;
// all call sites keep lds offset strictly linear in the per-lane loop index)
__device__ __forceinline__ void gload_lds16(void* lds, const void* g) {
  __builtin_amdgcn_global_load_lds(
      (const __attribute__((address_space(1))) unsigned int*)g,
      (__attribute__((address_space(3))) unsigned int*)lds, 16, 0, 0);
}

// ---------------------------------------------------------------------------
// Zero the 1-pixel border of all three planar activation buffers in ONE
// launch: feat [16][4][258][258][8], actA/actB [16][8][258][258][8] fp16.
// (ws is re-poisoned 0xAA before every launch, so this runs every call.)
// ---------------------------------------------------------------------------
__global__ __launch_bounds__(256) void zero_border3(_Float16* __restrict__ f,
                                                    _Float16* __restrict__ a,
                                                    _Float16* __restrict__ bb) {
  int idx = blockIdx.x * 256 + threadIdx.x;
  int total = 16 * 20 * 1028;
  if (idx >= total) return;
  int p = idx % 1028;
  int rest = idx / 1028;
  int cg = rest % 20;
  int b = rest / 20;
  _Float16* buf;
  int ncg, c;
  if (cg < 4) { buf = f; ncg = 4; c = cg; }
  else if (cg < 12) { buf = a; ncg = 8; c = cg - 4; }
  else { buf = bb; ncg = 8; c = cg - 12; }
  int row, col;
  if (p < 258) { row = 0; col = p; }
  else if (p < 516) { row = 257; col = p - 258; }
  else if (p < 772) { row = p - 515; col = 0; }
  else { row = p - 771; col = 257; }
  *(floatx4*)&buf[(((size_t)(b * ncg + c) * P_ + row) * P_ + col) * 8] =
      (floatx4)0.f;
}

// ---------------------------------------------------------------------------
// Feature extraction: x [B,3,H,W] fp32 -> F planar [B][4][258][258][8] fp16
// ---------------------------------------------------------------------------
__global__ __launch_bounds__(256) void feat_kernel(const float* __restrict__ x,
                                                   _Float16* __restrict__ F) {
  __shared__ float sg[36][37];
  __shared__ float sgr[36][37];

  const int b = blockIdx.z;
  const int y0 = blockIdx.y * 32;
  const int x0 = blockIdx.x * 32;
  const float* xb = x + (size_t)b * 3 * HW_;

  for (int i = threadIdx.x; i < 36 * 36; i += 256) {
    int iy = i / 36, ix = i % 36;
    int gy = y0 + iy - 2, gx = x0 + ix - 2;
    float gray = 0.f, green = 0.f;
    if (gy >= 0 && gy < H_ && gx >= 0 && gx < W_) {
      int idx = gy * W_ + gx;
      float r = fminf(fmaxf(xb[idx] * 0.229f + 0.485f, 0.f), 1.f);
      float g = fminf(fmaxf(xb[idx + HW_] * 0.224f + 0.456f, 0.f), 1.f);
      float bl = fminf(fmaxf(xb[idx + 2 * HW_] * 0.225f + 0.406f, 0.f), 1.f);
      gray = 0.299f * r + 0.587f * g + 0.114f * bl;
      green = g;
    }
    sg[iy][ix] = gray;
    sgr[iy][ix] = green;
  }
  __syncthreads();

  for (int p = threadIdx.x; p < 32 * 32; p += 256) {
    const int py = p >> 5, px = p & 31;
    const int ly = py + 2, lx = px + 2;
#define G(dy, dx) sg[ly + (dy)][lx + (dx)]
    float f[32];
    const float c = G(0, 0);

    {
      const float ga[5] = {1.f, 4.f, 6.f, 4.f, 1.f};
      float s = 0.f;
#pragma unroll
      for (int i = 0; i < 5; i++) {
        float rs = 0.f;
#pragma unroll
        for (int j = 0; j < 5; j++) rs += ga[j] * G(i - 2, j - 2);
        s += ga[i] * rs;
      }
      f[0] = c - s * (1.0f / 256.0f);
    }

    const int dy8[8] = {-1, -1, 0, 1, 1, 1, 0, -1};
    const int dx8[8] = {0, 1, 1, 1, 0, -1, -1, -1};

#pragma unroll
    for (int k = 0; k < 8; k++) f[1 + k] = G(dy8[k], dx8[k]) - c;
#pragma unroll
    for (int k = 0; k < 4; k++)
      f[9 + k] = 0.5f * (G(dy8[k], dx8[k]) + G(-dy8[k], -dx8[k])) - c;
#pragma unroll
    for (int k = 0; k < 8; k++)
      f[13 + k] = (-G(-dy8[k], -dx8[k]) + 3.f * c - 3.f * G(dy8[k], dx8[k]) +
                   G(2 * dy8[k], 2 * dx8[k])) * (1.f / 3.f);

    {
      const float sq3[3][3] = {{-1, 2, -1}, {2, -4, 2}, {-1, 2, -1}};
      float s = 0.f;
#pragma unroll
      for (int i = 0; i < 3; i++)
#pragma unroll
        for (int j = 0; j < 3; j++) s += sq3[i][j] * G(i - 1, j - 1);
      f[21] = s * 0.25f;
    }
    {
      const float sq5[5][5] = {{-1, 2, -2, 2, -1},
                               {2, -6, 8, -6, 2},
                               {-2, 8, -12, 8, -2},
                               {2, -6, 8, -6, 2},
                               {-1, 2, -2, 2, -1}};
      float s = 0.f;
#pragma unroll
      for (int i = 0; i < 5; i++)
#pragma unroll
        for (int j = 0; j < 5; j++) s += sq5[i][j] * G(i - 2, j - 2);
      f[22] = s * (1.0f / 12.0f);
    }
    {
      const float e3[3][3] = {{-1, 2, -1}, {2, -4, 2}, {0, 0, 0}};
      float s0 = 0.f, s1 = 0.f, s2 = 0.f, s3 = 0.f;
#pragma unroll
      for (int i = 0; i < 3; i++)
#pragma unroll
        for (int j = 0; j < 3; j++) {
          float v = G(i - 1, j - 1);
          s0 += e3[i][j] * v;
          s1 += e3[j][2 - i] * v;
          s2 += e3[2 - i][2 - j] * v;
          s3 += e3[2 - j][i] * v;
        }
      f[23] = s0 * 0.25f;
      f[24] = s1 * 0.25f;
      f[25] = s2 * 0.25f;
      f[26] = s3 * 0.25f;
    }
    {
      const float e5[5][5] = {{-1, 2, -2, 2, -1},
                              {2, -6, 8, -6, 2},
                              {-2, 8, -12, 8, -2},
                              {0, 0, 0, 0, 0},
                              {0, 0, 0, 0, 0}};
      float s0 = 0.f, s1 = 0.f, s2 = 0.f, s3 = 0.f;
#pragma unroll
      for (int i = 0; i < 5; i++)
#pragma unroll
        for (int j = 0; j < 5; j++) {
          float v = G(i - 2, j - 2);
          s0 += e5[i][j] * v;
          s1 += e5[j][4 - i] * v;
          s2 += e5[4 - i][4 - j] * v;
          s3 += e5[4 - j][i] * v;
        }
      f[27] = s0 * 0.25f;
      f[28] = s1 * 0.25f;
      f[29] = s2 * 0.25f;
      f[30] = s3 * 0.25f;
    }
    {
      float gc = sgr[ly][lx];
      f[31] = gc - 0.25f * (sgr[ly - 1][lx] + sgr[ly][lx - 1] +
                            sgr[ly][lx + 1] + sgr[ly + 1][lx]);
    }
#undef G

    _Float16 h[32];
#pragma unroll
    for (int cc = 0; cc < 32; cc++) h[cc] = (_Float16)f[cc];
    const floatx4* src = (const floatx4*)h;
#pragma unroll
    for (int cg = 0; cg < 4; cg++)
      *(floatx4*)&F[(((size_t)(b * 4 + cg) * P_ + (y0 + py + 1)) * P_ +
                     (x0 + px + 1)) * 8] = src[cg];
  }
}

// ---------------------------------------------------------------------------
// Weight prep (all 4 layers in ONE launch, blockIdx.y = layer):
// OIHW fp32 -> [cin/8][9][64][8] fp16 + folded BN scale/shift.
// ---------------------------------------------------------------------------
__global__ void wprep4_kernel(
    const float* __restrict__ w1, const float* __restrict__ b1,
    const float* __restrict__ g1, const float* __restrict__ be1,
    const float* __restrict__ m1, const float* __restrict__ v1,
    const float* __restrict__ w2, const float* __restrict__ b2,
    const float* __restrict__ g2, const float* __restrict__ be2,
    const float* __restrict__ m2, const float* __restrict__ v2,
    const float* __restrict__ w3, const float* __restrict__ b3,
    const float* __restrict__ g3, const float* __restrict__ be3,
    const float* __restrict__ m3, const float* __restrict__ v3,
    const float* __restrict__ w4, const float* __restrict__ b4,
    const float* __restrict__ g4, const float* __restrict__ be4,
    const float* __restrict__ m4, const float* __restrict__ v4,
    _Float16* __restrict__ wp1, _Float16* __restrict__ wp2,
    _Float16* __restrict__ wp3, _Float16* __restrict__ wp4,
    float* __restrict__ scsh) {
  const int layer = blockIdx.y;
  const float *w, *bias, *g, *be, *m, *v;
  _Float16* wp;
  int cin;
  switch (layer) {
    case 0: w = w1; bias = b1; g = g1; be = be1; m = m1; v = v1; wp = wp1; cin = 32; break;
    case 1: w = w2; bias = b2; g = g2; be = be2; m = m2; v = v2; wp = wp2; cin = 64; break;
    case 2: w = w3; bias = b3; g = g3; be = be3; m = m3; v = v3; wp = wp3; cin = 64; break;
    default: w = w4; bias = b4; g = g4; be = be4; m = m4; v = v4; wp = wp4; cin = 64; break;
  }
  int i = blockIdx.x * 256 + threadIdx.x;
  int total = cin * 9 * 64;
  if (i < total) {
    int j = i & 7;
    int co = (i >> 3) & 63;
    int rest = i >> 9;
    int t = rest % 9;
    int qc = rest / 9;
    int ci = qc * 8 + j;
    wp[i] = (_Float16)w[((size_t)co * cin + ci) * 9 + t];
  }
  if (i < 64) {
    float s = g[i] * rsqrtf(v[i] + 1e-5f);
    scsh[layer * 128 + i] = s;
    scsh[layer * 128 + 64 + i] = be[i] + (bias[i] - m[i]) * s;
  }
}

// ---------------------------------------------------------------------------
// Implicit-GEMM conv3x3 + BN + ReLU via mfma_f32_16x16x32_f16.
// in: PLANAR fp16 [B][CIN/8][258][258][8].  wp: [CIN/8][9][64][8] fp16.
// Block: 64(x) x 8(y) pixels, all 64 couts. 4 waves; wave w owns rows 2w,2w+1.
// Wave tile: M=128 x N=64 = 8x4 MFMA tiles.
//
// ROUND-1 structure restored (2 blocks/CU, per-kc stage + barrier — the
// cross-block TLP hides the drain; round-2's stage-once @1 block/CU lost it).
// NEW: weights are NOT staged in LDS. B-fragments load per-tap straight from
// global (L2-hot: 74KB/layer shared by all blocks; ~6.5 B/cyc/CU average,
// far under the 56 B/cyc L2 ceiling). This halves the per-kc stage+drain
// (79KB -> 42KB input only) and cuts LDS reads 12 -> 8 per tap.
// LDS = 42,240B/block -> still 2 blocks/CU (VGPR ~210 caps at 2 waves/SIMD).
// FINAL=false: planar fp16 out via two per-wave 8KB LDS bounce passes
// (42KB can't hold the old 64KB one-pass bounce). FINAL=true: NCHW fp32.
// ---------------------------------------------------------------------------
template <int CIN, bool FINAL>
__global__ __launch_bounds__(256, 2) void conv_mfma(
    const _Float16* __restrict__ in, const _Float16* __restrict__ wp,
    const float* __restrict__ sc, const float* __restrict__ sh,
    void* __restrict__ outv) {
  __shared__ char smem[42240];  // input tile [4][10][66][8] fp16
  _Float16(*s_in)[10][66][8] = (_Float16(*)[10][66][8])smem;

  const int tid = threadIdx.x;
  const int b = blockIdx.z;
  const int y0 = blockIdx.y * 8;
  const int x0 = blockIdx.x * 64;
  const int wid = tid >> 6;
  const int lane = tid & 63;
  const int quad = lane >> 4;
  const int ln = lane & 15;

  floatx4 acc[8][4];
#pragma unroll
  for (int mt = 0; mt < 8; mt++)
#pragma unroll
    for (int nt = 0; nt < 4; nt++) acc[mt][nt] = (floatx4)0.f;

  for (int kc = 0; kc < CIN / 32; kc++) {
    __syncthreads();
    // input stage: 2640 16B units; LDS offset linear in i; global address
    // contiguous in i within each (q,row) segment (planar layout)
    for (int i = tid; i < 2640; i += 256) {
      int q = i / 660, rem = i % 660;
      int row = rem / 66, col = rem % 66;
      gload_lds16(smem + i * 16,
                  &in[(((size_t)(b * (CIN / 8) + kc * 4 + q) * P_ +
                        (y0 + row)) * P_ + (x0 + col)) * 8]);
    }
    __syncthreads();

    // per-lane weight base for this kc's plane group (quad selects plane)
    const _Float16* wq = wp + (size_t)(kc * 4 + quad) * 9 * 512;
#pragma unroll
    for (int t = 0; t < 9; t++) {
      const int ty = t / 3, tx = t % 3;
      half8 a[8], bb[4];
#pragma unroll
      for (int nt = 0; nt < 4; nt++)
        bb[nt] = *(const half8*)&wq[t * 512 + (nt * 16 + ln) * 8];
#pragma unroll
      for (int mt = 0; mt < 8; mt++)
        a[mt] = *(const half8*)&s_in[quad][2 * wid + ty + (mt >> 2)]
                                    [(mt & 3) * 16 + ln + tx][0];
#pragma unroll
      for (int mt = 0; mt < 8; mt++)
#pragma unroll
        for (int nt = 0; nt < 4; nt++)
          acc[mt][nt] = __builtin_amdgcn_mfma_f32_16x16x32_f16(
              a[mt], bb[nt], acc[mt][nt], 0, 0, 0);
    }
  }

  if (FINAL) {
    // NCHW fp32 direct: in-lane 4 accs = 4 consecutive x -> dwordx4 stores
    float* out = (float*)outv;
#pragma unroll
    for (int nt = 0; nt < 4; nt++) {
      int co = nt * 16 + ln;
      float s = sc[co], t0 = sh[co];
#pragma unroll
      for (int mt = 0; mt < 8; mt++) {
        int y = y0 + 2 * wid + (mt >> 2);
        int xb = x0 + (mt & 3) * 16 + quad * 4;
        floatx4 vv;
#pragma unroll
        for (int r = 0; r < 4; r++) vv[r] = fmaxf(acc[mt][nt][r] * s + t0, 0.f);
        *(floatx4*)&out[(((size_t)b * 64 + co) * H_ + y) * W_ + xb] = vv;
      }
    }
  } else {
    // planar fp16 out via per-wave LDS bounce, two 8KB passes (one per
    // output row of the wave). Region per wave = 5280 halves (10,560B);
    // 4 waves use the full 42,240B smem. XOR-swizzle spreads the
    // plane-major 16B re-read across banks (same pattern as before).
    __syncthreads();  // all MFMA LDS reads done before overwrite
    _Float16* s_out = (_Float16*)smem + wid * 5280;
    _Float16* out = (_Float16*)outv;
#pragma unroll
    for (int h = 0; h < 2; h++) {
      // RAW/WAR guard between passes (per-wave private region, cross-lane)
      asm volatile("s_waitcnt lgkmcnt(0)" ::: "memory");
#pragma unroll
      for (int nt = 0; nt < 4; nt++) {
        int co = nt * 16 + ln;
        float s = sc[co], t0 = sh[co];
        int cog = co >> 3, clo = co & 7;
#pragma unroll
        for (int mt2 = 0; mt2 < 4; mt2++) {
          int lpix0 = mt2 * 16 + quad * 4;
#pragma unroll
          for (int r = 0; r < 4; r++) {
            int lpix = lpix0 + r;
            s_out[lpix * 64 + (((cog ^ (lpix & 7)) << 3) | clo)] =
                (_Float16)fmaxf(acc[h * 4 + mt2][nt][r] * s + t0, 0.f);
          }
        }
      }
      asm volatile("s_waitcnt lgkmcnt(0)" ::: "memory");
      int gy = y0 + 2 * wid + h + 1;
#pragma unroll
      for (int cog = 0; cog < 8; cog++) {
        *(floatx4*)&out[(((size_t)(b * 8 + cog) * P_ + gy) * P_ +
                         (x0 + lane + 1)) * 8] =
            *(const floatx4*)&s_out[lane * 64 + ((cog ^ (lane & 7)) << 3)];
      }
    }
  }
}

// ---------------------------------------------------------------------------
// Launch
// ---------------------------------------------------------------------------
extern "C" void kernel_launch(void* const* d_in, const int* in_sizes, int n_in,
                              void* d_out, int out_size, void* d_ws,
                              size_t ws_size, hipStream_t stream) {
  const float* x = (const float*)d_in[0];
#define LAYER_PTRS(i)                                                       \
  const float* w##i = (const float*)d_in[1 + ((i)-1) * 6 + 0];              \
  const float* b##i = (const float*)d_in[1 + ((i)-1) * 6 + 1];              \
  const float* g##i = (const float*)d_in[1 + ((i)-1) * 6 + 2];              \
  const float* be##i = (const float*)d_in[1 + ((i)-1) * 6 + 3];             \
  const float* m##i = (const float*)d_in[1 + ((i)-1) * 6 + 4];              \
  const float* v##i = (const float*)d_in[1 + ((i)-1) * 6 + 5];
  LAYER_PTRS(1)
  LAYER_PTRS(2)
  LAYER_PTRS(3)
  LAYER_PTRS(4)
#undef LAYER_PTRS

  char* ws = (char*)d_ws;
  const size_t featB = (size_t)16 * 4 * P_ * P_ * 8 * 2;   // 68,161,536
  const size_t actB64 = (size_t)16 * 8 * P_ * P_ * 8 * 2;  // 136,323,072
  _Float16* feat = (_Float16*)ws;
  _Float16* actA = (_Float16*)(ws + featB);
  _Float16* actB = (_Float16*)(ws + featB + actB64);
  char* wbase = ws + featB + 2 * actB64;
  _Float16* wp1 = (_Float16*)(wbase);
  _Float16* wp2 = (_Float16*)(wbase + 36864);
  _Float16* wp3 = (_Float16*)(wbase + 36864 + 73728);
  _Float16* wp4 = (_Float16*)(wbase + 36864 + 2 * 73728);
  float* scsh = (float*)(wbase + 36864 + 3 * 73728);
  float *sc1 = scsh, *sh1 = scsh + 64;
  float *sc2 = scsh + 128, *sh2 = scsh + 192;
  float *sc3 = scsh + 256, *sh3 = scsh + 320;
  float *sc4 = scsh + 384, *sh4 = scsh + 448;

  dim3 wgrid(144, 4);
  wprep4_kernel<<<wgrid, 256, 0, stream>>>(
      w1, b1, g1, be1, m1, v1, w2, b2, g2, be2, m2, v2,
      w3, b3, g3, be3, m3, v3, w4, b4, g4, be4, m4, v4,
      wp1, wp2, wp3, wp4, scsh);

  zero_border3<<<1285, 256, 0, stream>>>(feat, actA, actB);

  dim3 fgrid(W_ / 32, H_ / 32, B_);
  feat_kernel<<<fgrid, 256, 0, stream>>>(x, feat);

  dim3 cgrid(W_ / 64, H_ / 8, B_);
  conv_mfma<32, false><<<cgrid, 256, 0, stream>>>(feat, wp1, sc1, sh1, actA);
  conv_mfma<64, false><<<cgrid, 256, 0, stream>>>(actA, wp2, sc2, sh2, actB);
  conv_mfma<64, false><<<cgrid, 256, 0, stream>>>(actB, wp3, sc3, sh3, actA);
  conv_mfma<64, true><<<cgrid, 256, 0, stream>>>(actA, wp4, sc4, sh4, d_out);
}

// Round 4
// 624.574 us; speedup vs baseline: 1.1844x; 1.1159x over previous
//
#include <hip/hip_runtime.h>
#include <hip/hip_bf16.h>
#include <cstddef>

#define B_ 16
#define H_ 256
#define W_ 256
#define HW_ (H_ * W_)
#define P_ 258  // padded H/W for planar activation buffers

// Activation layout is channel-group-PLANAR: [B][C/8][258][258][8] fp16.
// Plane q holds channels q*8..q*8+7. Conv stage-DMA global addresses are
// contiguous in the staging loop index (1KB coalesced per wave instruction)
// while the LDS layout s_in[q][row][col][8] matches MFMA fragment needs.

typedef _Float16 half8 __attribute__((ext_vector_type(8)));
typedef float floatx4 __attribute__((ext_vector_type(4)));

// async global->LDS 16B DMA (LDS dest must be wave-uniform base + lane*16;
// all call sites keep lds offset strictly linear in the per-lane loop index)
__device__ __forceinline__ void gload_lds16(void* lds, const void* g) {
  __builtin_amdgcn_global_load_lds(
      (const __attribute__((address_space(1))) unsigned int*)g,
      (__attribute__((address_space(3))) unsigned int*)lds, 16, 0, 0);
}

// ---------------------------------------------------------------------------
// Zero the 1-pixel border of all three planar activation buffers in ONE
// launch: feat [16][4][258][258][8], actA/actB [16][8][258][258][8] fp16.
// (ws is re-poisoned 0xAA before every launch, so this runs every call.)
// ---------------------------------------------------------------------------
__global__ __launch_bounds__(256) void zero_border3(_Float16* __restrict__ f,
                                                    _Float16* __restrict__ a,
                                                    _Float16* __restrict__ bb) {
  int idx = blockIdx.x * 256 + threadIdx.x;
  int total = 16 * 20 * 1028;
  if (idx >= total) return;
  int p = idx % 1028;
  int rest = idx / 1028;
  int cg = rest % 20;
  int b = rest / 20;
  _Float16* buf;
  int ncg, c;
  if (cg < 4) { buf = f; ncg = 4; c = cg; }
  else if (cg < 12) { buf = a; ncg = 8; c = cg - 4; }
  else { buf = bb; ncg = 8; c = cg - 12; }
  int row, col;
  if (p < 258) { row = 0; col = p; }
  else if (p < 516) { row = 257; col = p - 258; }
  else if (p < 772) { row = p - 515; col = 0; }
  else { row = p - 771; col = 257; }
  *(floatx4*)&buf[(((size_t)(b * ncg + c) * P_ + row) * P_ + col) * 8] =
      (floatx4)0.f;
}

// ---------------------------------------------------------------------------
// Feature extraction: x [B,3,H,W] fp32 -> F planar [B][4][258][258][8] fp16
// ---------------------------------------------------------------------------
__global__ __launch_bounds__(256) void feat_kernel(const float* __restrict__ x,
                                                   _Float16* __restrict__ F) {
  __shared__ float sg[36][37];
  __shared__ float sgr[36][37];

  const int b = blockIdx.z;
  const int y0 = blockIdx.y * 32;
  const int x0 = blockIdx.x * 32;
  const float* xb = x + (size_t)b * 3 * HW_;

  for (int i = threadIdx.x; i < 36 * 36; i += 256) {
    int iy = i / 36, ix = i % 36;
    int gy = y0 + iy - 2, gx = x0 + ix - 2;
    float gray = 0.f, green = 0.f;
    if (gy >= 0 && gy < H_ && gx >= 0 && gx < W_) {
      int idx = gy * W_ + gx;
      float r = fminf(fmaxf(xb[idx] * 0.229f + 0.485f, 0.f), 1.f);
      float g = fminf(fmaxf(xb[idx + HW_] * 0.224f + 0.456f, 0.f), 1.f);
      float bl = fminf(fmaxf(xb[idx + 2 * HW_] * 0.225f + 0.406f, 0.f), 1.f);
      gray = 0.299f * r + 0.587f * g + 0.114f * bl;
      green = g;
    }
    sg[iy][ix] = gray;
    sgr[iy][ix] = green;
  }
  __syncthreads();

  for (int p = threadIdx.x; p < 32 * 32; p += 256) {
    const int py = p >> 5, px = p & 31;
    const int ly = py + 2, lx = px + 2;
#define G(dy, dx) sg[ly + (dy)][lx + (dx)]
    float f[32];
    const float c = G(0, 0);

    {
      const float ga[5] = {1.f, 4.f, 6.f, 4.f, 1.f};
      float s = 0.f;
#pragma unroll
      for (int i = 0; i < 5; i++) {
        float rs = 0.f;
#pragma unroll
        for (int j = 0; j < 5; j++) rs += ga[j] * G(i - 2, j - 2);
        s += ga[i] * rs;
      }
      f[0] = c - s * (1.0f / 256.0f);
    }

    const int dy8[8] = {-1, -1, 0, 1, 1, 1, 0, -1};
    const int dx8[8] = {0, 1, 1, 1, 0, -1, -1, -1};

#pragma unroll
    for (int k = 0; k < 8; k++) f[1 + k] = G(dy8[k], dx8[k]) - c;
#pragma unroll
    for (int k = 0; k < 4; k++)
      f[9 + k] = 0.5f * (G(dy8[k], dx8[k]) + G(-dy8[k], -dx8[k])) - c;
#pragma unroll
    for (int k = 0; k < 8; k++)
      f[13 + k] = (-G(-dy8[k], -dx8[k]) + 3.f * c - 3.f * G(dy8[k], dx8[k]) +
                   G(2 * dy8[k], 2 * dx8[k])) * (1.f / 3.f);

    {
      const float sq3[3][3] = {{-1, 2, -1}, {2, -4, 2}, {-1, 2, -1}};
      float s = 0.f;
#pragma unroll
      for (int i = 0; i < 3; i++)
#pragma unroll
        for (int j = 0; j < 3; j++) s += sq3[i][j] * G(i - 1, j - 1);
      f[21] = s * 0.25f;
    }
    {
      const float sq5[5][5] = {{-1, 2, -2, 2, -1},
                               {2, -6, 8, -6, 2},
                               {-2, 8, -12, 8, -2},
                               {2, -6, 8, -6, 2},
                               {-1, 2, -2, 2, -1}};
      float s = 0.f;
#pragma unroll
      for (int i = 0; i < 5; i++)
#pragma unroll
        for (int j = 0; j < 5; j++) s += sq5[i][j] * G(i - 2, j - 2);
      f[22] = s * (1.0f / 12.0f);
    }
    {
      const float e3[3][3] = {{-1, 2, -1}, {2, -4, 2}, {0, 0, 0}};
      float s0 = 0.f, s1 = 0.f, s2 = 0.f, s3 = 0.f;
#pragma unroll
      for (int i = 0; i < 3; i++)
#pragma unroll
        for (int j = 0; j < 3; j++) {
          float v = G(i - 1, j - 1);
          s0 += e3[i][j] * v;
          s1 += e3[j][2 - i] * v;
          s2 += e3[2 - i][2 - j] * v;
          s3 += e3[2 - j][i] * v;
        }
      f[23] = s0 * 0.25f;
      f[24] = s1 * 0.25f;
      f[25] = s2 * 0.25f;
      f[26] = s3 * 0.25f;
    }
    {
      const float e5[5][5] = {{-1, 2, -2, 2, -1},
                              {2, -6, 8, -6, 2},
                              {-2, 8, -12, 8, -2},
                              {0, 0, 0, 0, 0},
                              {0, 0, 0, 0, 0}};
      float s0 = 0.f, s1 = 0.f, s2 = 0.f, s3 = 0.f;
#pragma unroll
      for (int i = 0; i < 5; i++)
#pragma unroll
        for (int j = 0; j < 5; j++) {
          float v = G(i - 2, j - 2);
          s0 += e5[i][j] * v;
          s1 += e5[j][4 - i] * v;
          s2 += e5[4 - i][4 - j] * v;
          s3 += e5[4 - j][i] * v;
        }
      f[27] = s0 * 0.25f;
      f[28] = s1 * 0.25f;
      f[29] = s2 * 0.25f;
      f[30] = s3 * 0.25f;
    }
    {
      float gc = sgr[ly][lx];
      f[31] = gc - 0.25f * (sgr[ly - 1][lx] + sgr[ly][lx - 1] +
                            sgr[ly][lx + 1] + sgr[ly + 1][lx]);
    }
#undef G

    _Float16 h[32];
#pragma unroll
    for (int cc = 0; cc < 32; cc++) h[cc] = (_Float16)f[cc];
    const floatx4* src = (const floatx4*)h;
#pragma unroll
    for (int cg = 0; cg < 4; cg++)
      *(floatx4*)&F[(((size_t)(b * 4 + cg) * P_ + (y0 + py + 1)) * P_ +
                     (x0 + px + 1)) * 8] = src[cg];
  }
}

// ---------------------------------------------------------------------------
// Weight prep (all 4 layers in ONE launch, blockIdx.y = layer):
// OIHW fp32 -> [cin/8][9][64][8] fp16 + folded BN scale/shift.
// ---------------------------------------------------------------------------
__global__ void wprep4_kernel(
    const float* __restrict__ w1, const float* __restrict__ b1,
    const float* __restrict__ g1, const float* __restrict__ be1,
    const float* __restrict__ m1, const float* __restrict__ v1,
    const float* __restrict__ w2, const float* __restrict__ b2,
    const float* __restrict__ g2, const float* __restrict__ be2,
    const float* __restrict__ m2, const float* __restrict__ v2,
    const float* __restrict__ w3, const float* __restrict__ b3,
    const float* __restrict__ g3, const float* __restrict__ be3,
    const float* __restrict__ m3, const float* __restrict__ v3,
    const float* __restrict__ w4, const float* __restrict__ b4,
    const float* __restrict__ g4, const float* __restrict__ be4,
    const float* __restrict__ m4, const float* __restrict__ v4,
    _Float16* __restrict__ wp1, _Float16* __restrict__ wp2,
    _Float16* __restrict__ wp3, _Float16* __restrict__ wp4,
    float* __restrict__ scsh) {
  const int layer = blockIdx.y;
  const float *w, *bias, *g, *be, *m, *v;
  _Float16* wp;
  int cin;
  switch (layer) {
    case 0: w = w1; bias = b1; g = g1; be = be1; m = m1; v = v1; wp = wp1; cin = 32; break;
    case 1: w = w2; bias = b2; g = g2; be = be2; m = m2; v = v2; wp = wp2; cin = 64; break;
    case 2: w = w3; bias = b3; g = g3; be = be3; m = m3; v = v3; wp = wp3; cin = 64; break;
    default: w = w4; bias = b4; g = g4; be = be4; m = m4; v = v4; wp = wp4; cin = 64; break;
  }
  int i = blockIdx.x * 256 + threadIdx.x;
  int total = cin * 9 * 64;
  if (i < total) {
    int j = i & 7;
    int co = (i >> 3) & 63;
    int rest = i >> 9;
    int t = rest % 9;
    int qc = rest / 9;
    int ci = qc * 8 + j;
    wp[i] = (_Float16)w[((size_t)co * cin + ci) * 9 + t];
  }
  if (i < 64) {
    float s = g[i] * rsqrtf(v[i] + 1e-5f);
    scsh[layer * 128 + i] = s;
    scsh[layer * 128 + 64 + i] = be[i] + (bias[i] - m[i]) * s;
  }
}

// ---------------------------------------------------------------------------
// Implicit-GEMM conv3x3 + BN + ReLU via mfma_f32_16x16x32_f16.
// in: PLANAR fp16 [B][CIN/8][258][258][8].  wp: [CIN/8][9][64][8] fp16.
// ROUND-1 structure (the 644us anchor): per-kc {stage input+weights -> drain
// -> barrier -> 9 taps x 32 MFMA}, 79KB LDS, 2 blocks/CU, 4 waves/block,
// wave w owns rows 2w,2w+1; wave tile M=128 x N=64 = 8x4 MFMA tiles.
//
// NEW (T1): XCD-chunked block swizzle. Grid is launched FLAT (2048 blocks);
// sid = (bid%8)*256 + bid/8 (bijective: 2048%8==0). Each XCD gets 256
// consecutive logical ids = 2 complete batch images, so y-adjacent blocks
// (25% input-row halo overlap) and the shared weight table hit the SAME
// per-XCD L2 instead of being scattered round-robin across 8 L2s.
// FINAL=false: out planar fp16 (64KB one-pass LDS bounce, XOR-swizzled).
// FINAL=true: out NCHW fp32 direct.
// ---------------------------------------------------------------------------
template <int CIN, bool FINAL>
__global__ __launch_bounds__(256, 2) void conv_mfma(
    const _Float16* __restrict__ in, const _Float16* __restrict__ wp,
    const float* __restrict__ sc, const float* __restrict__ sh,
    void* __restrict__ outv) {
  // single LDS block: s_in [4][10][66][8] (42,240B) then s_w [4][9][64][8]
  __shared__ char smem[42240 + 36864];
  _Float16(*s_in)[10][66][8] = (_Float16(*)[10][66][8])smem;
  _Float16(*s_w)[9][64][8] = (_Float16(*)[9][64][8])(smem + 42240);

  // XCD-chunked bijective swizzle of the flat 2048-block grid
  const int bid = blockIdx.x;
  const int sid = (bid & 7) * 256 + (bid >> 3);
  const int b = sid >> 7;           // batch  [0,16)
  const int y0 = ((sid >> 2) & 31) * 8;  // y-tile [0,32)*8
  const int x0 = (sid & 3) * 64;    // x-tile [0,4)*64

  const int tid = threadIdx.x;
  const int wid = tid >> 6;
  const int lane = tid & 63;
  const int quad = lane >> 4;
  const int ln = lane & 15;

  floatx4 acc[8][4];
#pragma unroll
  for (int mt = 0; mt < 8; mt++)
#pragma unroll
    for (int nt = 0; nt < 4; nt++) acc[mt][nt] = (floatx4)0.f;

  for (int kc = 0; kc < CIN / 32; kc++) {
    __syncthreads();
    // input stage: 2640 16B units; LDS offset linear in i; global address
    // contiguous in i within each (q,row) segment (planar layout)
    for (int i = tid; i < 2640; i += 256) {
      int q = i / 660, rem = i % 660;
      int row = rem / 66, col = rem % 66;
      gload_lds16(smem + i * 16,
                  &in[(((size_t)(b * (CIN / 8) + kc * 4 + q) * P_ +
                        (y0 + row)) * P_ + (x0 + col)) * 8]);
    }
    // weight stage: 2304 16B units, global layout == LDS layout
    for (int i = tid; i < 2304; i += 256) {
      gload_lds16(smem + 42240 + i * 16, wp + ((size_t)kc * 2304 + i) * 8);
    }
    __syncthreads();

#pragma unroll
    for (int t = 0; t < 9; t++) {
      const int ty = t / 3, tx = t % 3;
      half8 a[8], bb[4];
#pragma unroll
      for (int nt = 0; nt < 4; nt++)
        bb[nt] = *(const half8*)&s_w[quad][t][nt * 16 + ln][0];
#pragma unroll
      for (int mt = 0; mt < 8; mt++)
        a[mt] = *(const half8*)
            &s_in[quad][2 * wid + ty + (mt >> 2)][(mt & 3) * 16 + ln + tx][0];
#pragma unroll
      for (int mt = 0; mt < 8; mt++)
#pragma unroll
        for (int nt = 0; nt < 4; nt++)
          acc[mt][nt] = __builtin_amdgcn_mfma_f32_16x16x32_f16(
              a[mt], bb[nt], acc[mt][nt], 0, 0, 0);
    }
  }

  if (FINAL) {
    // NCHW fp32 direct: in-lane 4 accs = 4 consecutive x -> dwordx4 stores
    float* out = (float*)outv;
#pragma unroll
    for (int nt = 0; nt < 4; nt++) {
      int co = nt * 16 + ln;
      float s = sc[co], t0 = sh[co];
#pragma unroll
      for (int mt = 0; mt < 8; mt++) {
        int y = y0 + 2 * wid + (mt >> 2);
        int xb = x0 + (mt & 3) * 16 + quad * 4;
        floatx4 vv;
#pragma unroll
        for (int r = 0; r < 4; r++) vv[r] = fmaxf(acc[mt][nt][r] * s + t0, 0.f);
        *(floatx4*)&out[(((size_t)b * 64 + co) * H_ + y) * W_ + xb] = vv;
      }
    }
  } else {
    // planar fp16 out via per-wave 16KB LDS bounce (smem reused).
    // s_out logical layout: [pix 0..127][co 0..63], channel-group slot
    // XOR-swizzled by (pix&7) so the plane-major 16B re-read (lane = pix,
    // stride 128B) spreads across all 32 banks instead of hitting 4.
    __syncthreads();  // all MFMA LDS reads done before overwrite
    _Float16* s_out = (_Float16*)smem + wid * 8192;
#pragma unroll
    for (int nt = 0; nt < 4; nt++) {
      int co = nt * 16 + ln;
      float s = sc[co], t0 = sh[co];
      int cog = co >> 3, clo = co & 7;
#pragma unroll
      for (int mt = 0; mt < 8; mt++) {
        int pix0 = (mt >> 2) * 64 + (mt & 3) * 16 + quad * 4;
#pragma unroll
        for (int r = 0; r < 4; r++) {
          int pix = pix0 + r;
          s_out[pix * 64 + (((cog ^ (pix & 7)) << 3) | clo)] =
              (_Float16)fmaxf(acc[mt][nt][r] * s + t0, 0.f);
        }
      }
    }
    // cross-lane within-wave RAW guard before the redistributing re-read
    asm volatile("s_waitcnt lgkmcnt(0)" ::: "memory");
    _Float16* out = (_Float16*)outv;
#pragma unroll
    for (int k = 0; k < 16; k++) {
      int rw = k >> 3, cog = k & 7;
      int pix = rw * 64 + lane;
      int gy = y0 + 2 * wid + rw + 1, gx = x0 + lane + 1;
      *(floatx4*)&out[(((size_t)(b * 8 + cog) * P_ + gy) * P_ + gx) * 8] =
          *(const floatx4*)&s_out[pix * 64 + ((cog ^ (lane & 7)) << 3)];
    }
  }
}

// ---------------------------------------------------------------------------
// Launch
// ---------------------------------------------------------------------------
extern "C" void kernel_launch(void* const* d_in, const int* in_sizes, int n_in,
                              void* d_out, int out_size, void* d_ws,
                              size_t ws_size, hipStream_t stream) {
  const float* x = (const float*)d_in[0];
#define LAYER_PTRS(i)                                                       \
  const float* w##i = (const float*)d_in[1 + ((i)-1) * 6 + 0];              \
  const float* b##i = (const float*)d_in[1 + ((i)-1) * 6 + 1];              \
  const float* g##i = (const float*)d_in[1 + ((i)-1) * 6 + 2];              \
  const float* be##i = (const float*)d_in[1 + ((i)-1) * 6 + 3];             \
  const float* m##i = (const float*)d_in[1 + ((i)-1) * 6 + 4];              \
  const float* v##i = (const float*)d_in[1 + ((i)-1) * 6 + 5];
  LAYER_PTRS(1)
  LAYER_PTRS(2)
  LAYER_PTRS(3)
  LAYER_PTRS(4)
#undef LAYER_PTRS

  char* ws = (char*)d_ws;
  const size_t featB = (size_t)16 * 4 * P_ * P_ * 8 * 2;   // 68,161,536
  const size_t actB64 = (size_t)16 * 8 * P_ * P_ * 8 * 2;  // 136,323,072
  _Float16* feat = (_Float16*)ws;
  _Float16* actA = (_Float16*)(ws + featB);
  _Float16* actB = (_Float16*)(ws + featB + actB64);
  char* wbase = ws + featB + 2 * actB64;
  _Float16* wp1 = (_Float16*)(wbase);
  _Float16* wp2 = (_Float16*)(wbase + 36864);
  _Float16* wp3 = (_Float16*)(wbase + 36864 + 73728);
  _Float16* wp4 = (_Float16*)(wbase + 36864 + 2 * 73728);
  float* scsh = (float*)(wbase + 36864 + 3 * 73728);
  float *sc1 = scsh, *sh1 = scsh + 64;
  float *sc2 = scsh + 128, *sh2 = scsh + 192;
  float *sc3 = scsh + 256, *sh3 = scsh + 320;
  float *sc4 = scsh + 384, *sh4 = scsh + 448;

  dim3 wgrid(144, 4);
  wprep4_kernel<<<wgrid, 256, 0, stream>>>(
      w1, b1, g1, be1, m1, v1, w2, b2, g2, be2, m2, v2,
      w3, b3, g3, be3, m3, v3, w4, b4, g4, be4, m4, v4,
      wp1, wp2, wp3, wp4, scsh);

  zero_border3<<<1285, 256, 0, stream>>>(feat, actA, actB);

  dim3 fgrid(W_ / 32, H_ / 32, B_);
  feat_kernel<<<fgrid, 256, 0, stream>>>(x, feat);

  // flat 2048-block grids; XCD-chunked swizzle happens inside the kernel
  conv_mfma<32, false><<<2048, 256, 0, stream>>>(feat, wp1, sc1, sh1, actA);
  conv_mfma<64, false><<<2048, 256, 0, stream>>>(actA, wp2, sc2, sh2, actB);
  conv_mfma<64, false><<<2048, 256, 0, stream>>>(actB, wp3, sc3, sh3, actA);
  conv_mfma<64, true><<<2048, 256, 0, stream>>>(actA, wp4, sc4, sh4, d_out);
}